// Round 8
// baseline (614.516 us; speedup 1.0000x reference)
//
#include <hip/hip_runtime.h>
#include <hip/hip_bf16.h>

#define N_NODES 100000
#define N_EDGES 250000
#define N_REL 4
#define N_HEAD 4
#define D_HEAD 32
#define F_IN 256
#define F_HID 128
#define F_OUT 64
#define LRELU_SLOPE 0.2f

#define SCAN_B 256
#define NBLK ((N_NODES + SCAN_B - 1) / SCAN_B)   // 391

typedef __attribute__((ext_vector_type(8))) short s16x8;
typedef __attribute__((ext_vector_type(8))) unsigned short u16x8;
typedef __attribute__((ext_vector_type(4))) unsigned short u16x4;
typedef __attribute__((ext_vector_type(4))) float f32x4;

__device__ __forceinline__ float bf2f(unsigned short u) {
    return __uint_as_float(((unsigned int)u) << 16);
}
__device__ __forceinline__ unsigned short f2bf(float f) {
    unsigned int x = __float_as_uint(f);
    unsigned int r = x + 0x7fffu + ((x >> 16) & 1u);
    return (unsigned short)(r >> 16);
}
__device__ __forceinline__ void gload_lds16(const void* g, void* l) {
    __builtin_amdgcn_global_load_lds(
        (const __attribute__((address_space(1))) unsigned int*)g,
        (__attribute__((address_space(3))) unsigned int*)l, 16, 0, 0);
}

// ---------------- MFMA GEMM, relation-batched; rel = blockIdx.x (fast) for A-tile L2 reuse ----
// C[r][N,128] = A[N,FIN] @ Bt[r][128,FIN]^T   (A,Bt bf16 row-major; C bf16)
// MFMA operands SWAPPED (b as A-slot) so D holds 4 consecutive channels per lane -> 8B packed C stores.
template<int FIN>
__global__ __launch_bounds__(256) void gemm_mfma_k(const unsigned short* __restrict__ A,
                                                   const unsigned short* __restrict__ BtAll,
                                                   unsigned short* __restrict__ CAll) {
    const int rel = blockIdx.x;
    const unsigned short* Bt = BtAll + (size_t)rel * F_HID * FIN;
    unsigned short* C = CAll + (size_t)rel * N_NODES * F_HID;

    __shared__ short As[128 * 64];   // [row][k] bf16, XOR-swizzled chunks
    __shared__ short Bs[128 * 64];
    const int tid = threadIdx.x;
    const int lane = tid & 63;
    const int wave = tid >> 6;
    const int wr = wave >> 1, wc = wave & 1;
    const int row0 = blockIdx.y * 128;

    f32x4 acc[4][4];
#pragma unroll
    for (int m = 0; m < 4; ++m)
#pragma unroll
        for (int n = 0; n < 4; ++n) acc[m][n] = (f32x4)0.f;

    for (int k0 = 0; k0 < FIN; k0 += 64) {
        if (k0) __syncthreads();
#pragma unroll
        for (int i = 0; i < 4; ++i) {
            int flat = i * 256 + tid;
            int r = flat >> 3, ch = flat & 7;
            int sch = ch ^ (r & 7);
            int grow = row0 + r; if (grow > N_NODES - 1) grow = N_NODES - 1;
            gload_lds16(A + (size_t)grow * FIN + k0 + sch * 8, As + (size_t)flat * 8);
        }
#pragma unroll
        for (int i = 0; i < 4; ++i) {
            int flat = i * 256 + tid;
            int r = flat >> 3, ch = flat & 7;
            int sch = ch ^ (r & 7);
            gload_lds16(Bt + (size_t)r * FIN + k0 + sch * 8, Bs + (size_t)flat * 8);
        }
        __syncthreads();
#pragma unroll
        for (int kk = 0; kk < 2; ++kk) {
            s16x8 a[4], b[4];
            const int kb = kk * 64 + (lane >> 4) * 16;
#pragma unroll
            for (int m = 0; m < 4; ++m) {
                int r = wr * 64 + m * 16 + (lane & 15);
                int off = r * 128 + (kb ^ ((r & 7) << 4));
                a[m] = *(const s16x8*)((const char*)As + off);
            }
#pragma unroll
            for (int n = 0; n < 4; ++n) {
                int r = wc * 64 + n * 16 + (lane & 15);
                int off = r * 128 + (kb ^ ((r & 7) << 4));
                b[n] = *(const s16x8*)((const char*)Bs + off);
            }
            // swapped: b in A-slot, a in B-slot -> D row-dim = channels, col-dim = node rows
#pragma unroll
            for (int m = 0; m < 4; ++m)
#pragma unroll
                for (int n = 0; n < 4; ++n)
                    acc[m][n] = __builtin_amdgcn_mfma_f32_16x16x32_bf16(b[n], a[m], acc[m][n], 0, 0, 0);
        }
    }
    // epilogue: lane holds channels cbase..cbase+3 of node row r -> one 8B store per (m,n)
#pragma unroll
    for (int m = 0; m < 4; ++m) {
        int r = row0 + wr * 64 + m * 16 + (lane & 15);
        if (r < N_NODES) {
#pragma unroll
            for (int n = 0; n < 4; ++n) {
                int cbase = wc * 64 + n * 16 + (lane >> 4) * 4;
                u16x4 o = {f2bf(acc[m][n][0]), f2bf(acc[m][n][1]),
                           f2bf(acc[m][n][2]), f2bf(acc[m][n][3])};
                *(u16x4*)(C + (size_t)r * F_HID + cbase) = o;
            }
        }
    }
}

// ---------------- weight prep (merged): Wt[r][128][K] bf16 transpose + WAL[K][32] ----------------
template<int K>
__global__ __launch_bounds__(256) void wprep2_k(const float* __restrict__ W,
                                                const float* __restrict__ al,
                                                const float* __restrict__ ar,
                                                unsigned short* __restrict__ Wt,
                                                float* __restrict__ wal) {
    int i = blockIdx.x * 256 + threadIdx.x;
    if (i < N_REL * K * 128) {
        int r = i / (K * 128);
        int rem = i - r * K * 128;
        int k = rem >> 7, n = rem & 127;
        Wt[(size_t)r * 128 * K + (size_t)n * K + k] = f2bf(W[i]);
        return;
    }
    i -= N_REL * K * 128;
    if (i >= N_REL * K * 4) return;
    int rel = i / (K * 4);
    int rem = i - rel * K * 4;
    int f = rem >> 2, h = rem & 3;
    const float* wrow = W + ((size_t)rel * K + f) * F_HID + h * D_HEAD;
    const float* alv = al + ((size_t)rel * N_HEAD + h) * D_HEAD;
    const float* arv = ar + ((size_t)rel * N_HEAD + h) * D_HEAD;
    float sl = 0.f, sr = 0.f;
#pragma unroll
    for (int d = 0; d < D_HEAD; ++d) {
        float w = wrow[d];
        sl += w * alv[d];
        sr += w * arv[d];
    }
    wal[(size_t)f * 32 + rel * 4 + h] = sl;
    wal[(size_t)f * 32 + 16 + rel * 4 + h] = sr;
}

// el/er for ALL relations from hbf: EL[N,32] = hbf[N,FIN] @ WAL[FIN,32]
template<int FIN>
__global__ __launch_bounds__(256) void eler_wal_k(const unsigned short* __restrict__ hbf,
                                                  const float* __restrict__ wal,
                                                  float* __restrict__ el,
                                                  float* __restrict__ er) {
    __shared__ float walS[FIN * 32];
    for (int l = threadIdx.x; l < FIN * 8; l += 256)
        ((float4*)walS)[l] = ((const float4*)wal)[l];
    __syncthreads();
    const int jt = threadIdx.x & 3;
    const int rg = threadIdx.x >> 2;
    const int rbase = blockIdx.x * 256;
    float acc[4][8];
#pragma unroll
    for (int i = 0; i < 4; ++i)
#pragma unroll
        for (int o = 0; o < 8; ++o) acc[i][o] = 0.f;

    for (int f0 = 0; f0 < FIN; f0 += 8) {
        u16x8 hv8[4];
#pragma unroll
        for (int i = 0; i < 4; ++i) {
            int row = rbase + rg + 64 * i;
            hv8[i] = (row < N_NODES) ? *(const u16x8*)(hbf + (size_t)row * FIN + f0) : (u16x8)0;
        }
#pragma unroll
        for (int q = 0; q < 8; ++q) {
            float4 w0 = *(const float4*)&walS[(f0 + q) * 32 + jt * 8];
            float4 w1 = *(const float4*)&walS[(f0 + q) * 32 + jt * 8 + 4];
#pragma unroll
            for (int i = 0; i < 4; ++i) {
                float hv = bf2f(hv8[i][q]);
                acc[i][0] += hv * w0.x; acc[i][1] += hv * w0.y;
                acc[i][2] += hv * w0.z; acc[i][3] += hv * w0.w;
                acc[i][4] += hv * w1.x; acc[i][5] += hv * w1.y;
                acc[i][6] += hv * w1.z; acc[i][7] += hv * w1.w;
            }
        }
    }
#pragma unroll
    for (int i = 0; i < 4; ++i) {
        int row = rbase + rg + 64 * i;
        if (row < N_NODES) {
#pragma unroll
            for (int o = 0; o < 8; ++o) {
                int j = jt * 8 + o;
                int rel = (j >> 2) & 3, h = j & 3;
                float v = acc[i][o];
                if (j < 16) el[(size_t)rel * N_NODES * N_HEAD + row * 4 + h] = v;
                else        er[(size_t)rel * N_NODES * N_HEAD + row * 4 + h] = v;
            }
        }
    }
}

__global__ __launch_bounds__(256) void cast_k(const float* __restrict__ in,
                                              unsigned short* __restrict__ out, int n4) {
    int i = blockIdx.x * 256 + threadIdx.x;
    if (i >= n4) return;
    float4 v = *(const float4*)(in + (size_t)i * 4);
    u16x4 o = {f2bf(v.x), f2bf(v.y), f2bf(v.z), f2bf(v.w)};
    *(u16x4*)(out + (size_t)i * 4) = o;
}

// ---------------- CSR build ----------------
__global__ __launch_bounds__(256) void count_k(const int* __restrict__ dst, int* __restrict__ cnt) {
    int e = blockIdx.x * 256 + threadIdx.x;
    if (e >= N_EDGES) return;
    int r = blockIdx.y;
    atomicAdd(&cnt[r * N_NODES + dst[(size_t)r * N_EDGES + e]], 1);
}

__global__ __launch_bounds__(SCAN_B) void scan1_k(const int* __restrict__ cnt,
                                                  int* __restrict__ row, int* __restrict__ bsum) {
    __shared__ int sdata[SCAN_B];
    int r = blockIdx.y;
    int n = blockIdx.x * SCAN_B + threadIdx.x;
    int v = (n < N_NODES) ? cnt[r * N_NODES + n] : 0;
    sdata[threadIdx.x] = v;
    __syncthreads();
    for (int off = 1; off < SCAN_B; off <<= 1) {
        int t = (threadIdx.x >= off) ? sdata[threadIdx.x - off] : 0;
        __syncthreads();
        sdata[threadIdx.x] += t;
        __syncthreads();
    }
    if (n < N_NODES) row[r * (N_NODES + 1) + n] = sdata[threadIdx.x] - v;
    if (threadIdx.x == SCAN_B - 1) bsum[r * NBLK + blockIdx.x] = sdata[threadIdx.x];
}

__global__ __launch_bounds__(512) void scan2_k(int* __restrict__ bsum) {
    __shared__ int sdata[512];
    int r = blockIdx.x;
    int v = (threadIdx.x < NBLK) ? bsum[r * NBLK + threadIdx.x] : 0;
    sdata[threadIdx.x] = v;
    __syncthreads();
    for (int off = 1; off < 512; off <<= 1) {
        int t = (threadIdx.x >= off) ? sdata[threadIdx.x - off] : 0;
        __syncthreads();
        sdata[threadIdx.x] += t;
        __syncthreads();
    }
    if (threadIdx.x < NBLK) bsum[r * NBLK + threadIdx.x] = sdata[threadIdx.x] - v;
}

__global__ __launch_bounds__(256) void scan3_k(int* __restrict__ row, const int* __restrict__ bsum) {
    int r = blockIdx.y;
    int n = blockIdx.x * 256 + threadIdx.x;
    if (n > N_NODES) return;
    if (n == N_NODES) { row[r * (N_NODES + 1) + N_NODES] = N_EDGES; return; }
    row[r * (N_NODES + 1) + n] += bsum[r * NBLK + n / SCAN_B];
}

__global__ __launch_bounds__(256) void fill_k(const int* __restrict__ src, const int* __restrict__ dst,
                                              const int* __restrict__ row, int* __restrict__ cursor,
                                              int* __restrict__ csr_src) {
    int e = blockIdx.x * 256 + threadIdx.x;
    if (e >= N_EDGES) return;
    int r = blockIdx.y;
    int s = src[(size_t)r * N_EDGES + e];
    int d = dst[(size_t)r * N_EDGES + e];
    int p = row[r * (N_NODES + 1) + d] + atomicAdd(&cursor[r * N_NODES + d], 1);
    csr_src[(size_t)r * N_EDGES + p] = s;
}

// ---------------- fused: single-pass edge softmax + gather + bias + act ----------------
__global__ __launch_bounds__(256) void gather_fused_k(const int* __restrict__ csr_srcAll,
                                                      const int* __restrict__ rowAll,
                                                      const unsigned short* __restrict__ featAll,
                                                      const float* __restrict__ el,
                                                      const float* __restrict__ er,
                                                      const float* __restrict__ bias,  // [R][128]
                                                      unsigned short* __restrict__ hbf,
                                                      int relu) {
    int j = blockIdx.x * 256 + threadIdx.x;      // n*16 + sub
    if (j >= N_NODES * 16) return;
    int n = j >> 4, sub = j & 15;
    int h = sub >> 2;
    float acc[8];
#pragma unroll
    for (int q = 0; q < 8; ++q) acc[q] = 0.f;

#pragma unroll
    for (int rel = 0; rel < N_REL; ++rel) {
        const int* row = rowAll + (size_t)rel * (N_NODES + 1);
        const int* cs = csr_srcAll + (size_t)rel * N_EDGES;
        const float* elr = el + (size_t)rel * N_NODES * N_HEAD;
        const unsigned short* feat = featAll + (size_t)rel * N_NODES * F_HID;
        int st = row[n], en = row[n + 1];
        if (st == en) continue;
        float erd = er[(size_t)rel * N_NODES * N_HEAD + n * 4 + h];
        float sum = 0.f;
        float racc[8];
#pragma unroll
        for (int q = 0; q < 8; ++q) racc[q] = 0.f;
        for (int p = st; p < en; ++p) {
            int s = cs[p];
            float v = elr[s * 4 + h] + erd;
            v = v > 0.f ? v : LRELU_SLOPE * v;
            float ee = __expf(v);
            sum += ee;
            u16x8 f = *(const u16x8*)(feat + (size_t)s * F_HID + sub * 8);
#pragma unroll
            for (int q = 0; q < 8; ++q) racc[q] += ee * bf2f(f[q]);
        }
        float id = 1.f / fmaxf(sum, 1e-30f);
#pragma unroll
        for (int q = 0; q < 8; ++q) acc[q] += racc[q] * id;
    }

    int c0 = sub * 8;
    u16x8 o;
#pragma unroll
    for (int q = 0; q < 8; ++q) {
        int c = c0 + q;
        float bs = bias[c] + bias[128 + c] + bias[256 + c] + bias[384 + c];
        float t = acc[q] + bs;
        if (relu) t = fmaxf(t, 0.f);
        o[q] = f2bf(t);
    }
    *(u16x8*)(hbf + (size_t)n * F_HID + c0) = o;
}

// out[N,64] = H_bf16[N,128] @ W[128,64] + b
__global__ __launch_bounds__(256) void fc_k(const unsigned short* __restrict__ Hm,
                                            const float* __restrict__ Wm,
                                            const float* __restrict__ bv,
                                            float* __restrict__ out) {
    __shared__ float Ws[F_HID][F_OUT];
    __shared__ float Hs[32][F_HID];
    const int tid = threadIdx.x;
    const int n0 = blockIdx.x * 32;
    const int tx = tid & 63, ty = tid >> 6;
#pragma unroll
    for (int l = 0; l < 8; ++l) {
        int flat = tid + l * 256;
        int r = flat >> 4, c4 = flat & 15;
        *(float4*)(&Ws[r][c4 * 4]) = *(const float4*)(Wm + r * F_OUT + c4 * 4);
    }
#pragma unroll
    for (int l = 0; l < 2; ++l) {
        int flat = tid + l * 256;
        int r = flat >> 4, c8 = flat & 15;
        u16x8 v = (u16x8)0;
        if (n0 + r < N_NODES)
            v = *(const u16x8*)(Hm + (size_t)(n0 + r) * F_HID + c8 * 8);
#pragma unroll
        for (int q = 0; q < 8; ++q) Hs[r][c8 * 8 + q] = bf2f(v[q]);
    }
    __syncthreads();
    float acc[8];
#pragma unroll
    for (int i = 0; i < 8; ++i) acc[i] = 0.f;
    for (int k = 0; k < F_HID; ++k) {
        float w = Ws[k][tx];
#pragma unroll
        for (int i = 0; i < 8; ++i) acc[i] += Hs[ty * 8 + i][k] * w;
    }
    float bb = bv[tx];
#pragma unroll
    for (int i = 0; i < 8; ++i) {
        int r = n0 + ty * 8 + i;
        if (r < N_NODES) out[(size_t)r * F_OUT + tx] = acc[i] + bb;
    }
}

extern "C" void kernel_launch(void* const* d_in, const int* in_sizes, int n_in,
                              void* d_out, int out_size, void* d_ws, size_t ws_size,
                              hipStream_t stream) {
    const float* x   = (const float*)d_in[0];
    const int*   src = (const int*)d_in[1];
    const int*   dst = (const int*)d_in[2];
    const float* W[3]  = {(const float*)d_in[3], (const float*)d_in[7],  (const float*)d_in[11]};
    const float* al[3] = {(const float*)d_in[4], (const float*)d_in[8],  (const float*)d_in[12]};
    const float* ar[3] = {(const float*)d_in[5], (const float*)d_in[9],  (const float*)d_in[13]};
    const float* bb[3] = {(const float*)d_in[6], (const float*)d_in[10], (const float*)d_in[14]};
    const float* fcW = (const float*)d_in[15];
    const float* fcb = (const float*)d_in[16];
    float* out = (float*)d_out;

    // ---- workspace layout ----
    char* p = (char*)d_ws;
    unsigned short* hbf   = (unsigned short*)p; p += (size_t)N_NODES * F_IN * 2;           // 51.2 MB
    unsigned short* featb = (unsigned short*)p; p += (size_t)N_REL * N_NODES * F_HID * 2;  // 102.4 MB
    float* el    = (float*)p;               p += (size_t)N_REL * N_NODES * N_HEAD * 4;     // 6.4 MB
    float* er    = (float*)p;               p += (size_t)N_REL * N_NODES * N_HEAD * 4;
    float* wal0  = (float*)p;               p += (size_t)F_IN * 32 * 4;
    float* wal1  = (float*)p;               p += (size_t)F_HID * 32 * 4;
    float* wal2  = (float*)p;               p += (size_t)F_HID * 32 * 4;
    unsigned short* Wt0   = (unsigned short*)p; p += (size_t)N_REL * F_IN * F_HID * 2;
    unsigned short* Wt1   = (unsigned short*)p; p += (size_t)N_REL * F_HID * F_HID * 2;
    unsigned short* Wt2   = (unsigned short*)p; p += (size_t)N_REL * F_HID * F_HID * 2;
    int* cnt     = (int*)p;                 p += (size_t)N_REL * N_NODES * 4;
    int* cursor  = (int*)p;                 p += (size_t)N_REL * N_NODES * 4;
    int* rowp    = (int*)p;                 p += (size_t)N_REL * (N_NODES + 1) * 4;
    int* bsum    = (int*)p;                 p += (size_t)N_REL * NBLK * 4;
    int* csr_src = (int*)p;                 p += (size_t)N_REL * N_EDGES * 4;

    const int eblk = (N_EDGES + 255) / 256;
    const dim3 egrid(eblk, N_REL);

    // ---- prep (once per call) ----
    cast_k<<<(N_NODES * F_IN / 4 + 255) / 256, 256, 0, stream>>>(x, hbf, N_NODES * F_IN / 4);
    wprep2_k<F_IN><<<(N_REL * F_IN * 132 + 255) / 256, 256, 0, stream>>>(W[0], al[0], ar[0], Wt0, wal0);
    wprep2_k<F_HID><<<(N_REL * F_HID * 132 + 255) / 256, 256, 0, stream>>>(W[1], al[1], ar[1], Wt1, wal1);
    wprep2_k<F_HID><<<(N_REL * F_HID * 132 + 255) / 256, 256, 0, stream>>>(W[2], al[2], ar[2], Wt2, wal2);

    hipMemsetAsync(cnt, 0, 2 * (size_t)N_REL * N_NODES * sizeof(int), stream);
    count_k<<<egrid, 256, 0, stream>>>(dst, cnt);
    scan1_k<<<dim3(NBLK, N_REL), SCAN_B, 0, stream>>>(cnt, rowp, bsum);
    scan2_k<<<N_REL, 512, 0, stream>>>(bsum);
    scan3_k<<<dim3((N_NODES + 256) / 256, N_REL), 256, 0, stream>>>(rowp, bsum);
    fill_k<<<egrid, 256, 0, stream>>>(src, dst, rowp, cursor, csr_src);

    const dim3 gemm_grid(N_REL, (N_NODES + 127) / 128);          // rel fast-varying
    const int ew_blocks = (N_NODES + 255) / 256;                 // 391
    const int g_blocks  = (N_NODES * 16 + 255) / 256;            // 6250
    const int fc_blocks = (N_NODES + 31) / 32;

    const unsigned short* Wts[3] = {Wt0, Wt1, Wt2};
    const float* wals[3] = {wal0, wal1, wal2};

    for (int layer = 0; layer < 3; ++layer) {
        if (layer == 0) {
            gemm_mfma_k<F_IN><<<gemm_grid, 256, 0, stream>>>(hbf, Wts[0], featb);
            eler_wal_k<F_IN><<<ew_blocks, 256, 0, stream>>>(hbf, wals[0], el, er);
        } else {
            gemm_mfma_k<F_HID><<<gemm_grid, 256, 0, stream>>>(hbf, Wts[layer], featb);
            eler_wal_k<F_HID><<<ew_blocks, 256, 0, stream>>>(hbf, wals[layer], el, er);
        }
        gather_fused_k<<<g_blocks, 256, 0, stream>>>(csr_src, rowp, featb, el, er,
                                                     bb[layer], hbf, layer < 2 ? 1 : 0);
    }
    fc_k<<<fc_blocks, 256, 0, stream>>>(hbf, fcW, fcb, out);
}

// Round 9
// 520.975 us; speedup vs baseline: 1.1796x; 1.1796x over previous
//
#include <hip/hip_runtime.h>
#include <hip/hip_bf16.h>

#define N_NODES 100000
#define N_EDGES 250000
#define N_REL 4
#define N_HEAD 4
#define D_HEAD 32
#define F_IN 256
#define F_HID 128
#define F_OUT 64
#define LRELU_SLOPE 0.2f

#define SCAN_B 256
#define NBLK ((N_NODES + SCAN_B - 1) / SCAN_B)   // 391

typedef __attribute__((ext_vector_type(8))) short s16x8;
typedef __attribute__((ext_vector_type(8))) unsigned short u16x8;
typedef __attribute__((ext_vector_type(4))) unsigned short u16x4;
typedef __attribute__((ext_vector_type(4))) float f32x4;

__device__ __forceinline__ float bf2f(unsigned short u) {
    return __uint_as_float(((unsigned int)u) << 16);
}
__device__ __forceinline__ unsigned short f2bf(float f) {
    unsigned int x = __float_as_uint(f);
    unsigned int r = x + 0x7fffu + ((x >> 16) & 1u);
    return (unsigned short)(r >> 16);
}
__device__ __forceinline__ void gload_lds16(const void* g, void* l) {
    __builtin_amdgcn_global_load_lds(
        (const __attribute__((address_space(1))) unsigned int*)g,
        (__attribute__((address_space(3))) unsigned int*)l, 16, 0, 0);
}

// ---------------- MFMA GEMM, relation-batched; rel = blockIdx.x (fast) for A-tile L2 reuse ----
// rel<4: C[r][N,128] = A[N,FIN] @ Bt[r][128,FIN]^T (bf16 out)
// rel==4: el/er[R][N][H] = A @ WalBt[32,FIN]^T (f32 out, fused attention-logit GEMM)
// MFMA operands SWAPPED (b in A-slot): lane holds channels cbase..cbase+3 of node row r.
template<int FIN>
__global__ __launch_bounds__(256) void gemm_mfma_k(const unsigned short* __restrict__ A,
                                                   const unsigned short* __restrict__ BtAll,
                                                   const unsigned short* __restrict__ WalBt,
                                                   unsigned short* __restrict__ CAll,
                                                   float* __restrict__ el,
                                                   float* __restrict__ er) {
    const int rel = blockIdx.x;
    const unsigned short* Bt = (rel < N_REL) ? BtAll + (size_t)rel * F_HID * FIN : WalBt;

    __shared__ short As[128 * 64];   // [row][k] bf16, XOR-swizzled chunks
    __shared__ short Bs[128 * 64];
    const int tid = threadIdx.x;
    const int lane = tid & 63;
    const int wave = tid >> 6;
    const int wr = wave >> 1, wc = wave & 1;
    const int row0 = blockIdx.y * 128;

    f32x4 acc[4][4];
#pragma unroll
    for (int m = 0; m < 4; ++m)
#pragma unroll
        for (int n = 0; n < 4; ++n) acc[m][n] = (f32x4)0.f;

    for (int k0 = 0; k0 < FIN; k0 += 64) {
        if (k0) __syncthreads();
#pragma unroll
        for (int i = 0; i < 4; ++i) {
            int flat = i * 256 + tid;
            int r = flat >> 3, ch = flat & 7;
            int sch = ch ^ (r & 7);
            int grow = row0 + r; if (grow > N_NODES - 1) grow = N_NODES - 1;
            gload_lds16(A + (size_t)grow * FIN + k0 + sch * 8, As + (size_t)flat * 8);
        }
#pragma unroll
        for (int i = 0; i < 4; ++i) {
            int flat = i * 256 + tid;
            int r = flat >> 3, ch = flat & 7;
            int sch = ch ^ (r & 7);
            gload_lds16(Bt + (size_t)r * FIN + k0 + sch * 8, Bs + (size_t)flat * 8);
        }
        __syncthreads();
#pragma unroll
        for (int kk = 0; kk < 2; ++kk) {
            s16x8 a[4], b[4];
            const int kb = kk * 64 + (lane >> 4) * 16;
#pragma unroll
            for (int m = 0; m < 4; ++m) {
                int r = wr * 64 + m * 16 + (lane & 15);
                int off = r * 128 + (kb ^ ((r & 7) << 4));
                a[m] = *(const s16x8*)((const char*)As + off);
            }
#pragma unroll
            for (int n = 0; n < 4; ++n) {
                int r = wc * 64 + n * 16 + (lane & 15);
                int off = r * 128 + (kb ^ ((r & 7) << 4));
                b[n] = *(const s16x8*)((const char*)Bs + off);
            }
#pragma unroll
            for (int m = 0; m < 4; ++m)
#pragma unroll
                for (int n = 0; n < 4; ++n)
                    acc[m][n] = __builtin_amdgcn_mfma_f32_16x16x32_bf16(b[n], a[m], acc[m][n], 0, 0, 0);
        }
    }
    if (rel < N_REL) {
        unsigned short* C = CAll + (size_t)rel * N_NODES * F_HID;
#pragma unroll
        for (int m = 0; m < 4; ++m) {
            int r = row0 + wr * 64 + m * 16 + (lane & 15);
            if (r < N_NODES) {
#pragma unroll
                for (int n = 0; n < 4; ++n) {
                    int cbase = wc * 64 + n * 16 + (lane >> 4) * 4;
                    u16x4 o = {f2bf(acc[m][n][0]), f2bf(acc[m][n][1]),
                               f2bf(acc[m][n][2]), f2bf(acc[m][n][3])};
                    *(u16x4*)(C + (size_t)r * F_HID + cbase) = o;
                }
            }
        }
    } else if (wc == 0) {
        // cols 0..15 = el (rel = lane>>4, h = t), cols 16..31 = er
        int relh = lane >> 4;
#pragma unroll
        for (int m = 0; m < 4; ++m) {
            int r = row0 + wr * 64 + m * 16 + (lane & 15);
            if (r < N_NODES) {
                *(f32x4*)(el + (size_t)relh * N_NODES * N_HEAD + r * 4) = acc[m][0];
                *(f32x4*)(er + (size_t)relh * N_NODES * N_HEAD + r * 4) = acc[m][1];
            }
        }
    }
}

// ---------------- weight prep: Wt transpose + WalBt[128][K] bf16 (rows 32-127 zero) ----------------
template<int K>
__global__ __launch_bounds__(256) void wprep2_k(const float* __restrict__ W,
                                                const float* __restrict__ al,
                                                const float* __restrict__ ar,
                                                unsigned short* __restrict__ Wt,
                                                unsigned short* __restrict__ walbt) {
    int i = blockIdx.x * 256 + threadIdx.x;
    const int nWt = N_REL * K * 128;
    if (i < nWt) {
        int r = i / (K * 128);
        int rem = i - r * K * 128;
        int k = rem >> 7, n = rem & 127;
        Wt[(size_t)r * 128 * K + (size_t)n * K + k] = f2bf(W[i]);
        return;
    }
    i -= nWt;
    const int nWal = N_REL * K * 4;
    if (i < nWal) {
        int rel = i / (K * 4);
        int rem = i - rel * K * 4;
        int f = rem >> 2, h = rem & 3;
        const float* wrow = W + ((size_t)rel * K + f) * F_HID + h * D_HEAD;
        const float* alv = al + ((size_t)rel * N_HEAD + h) * D_HEAD;
        const float* arv = ar + ((size_t)rel * N_HEAD + h) * D_HEAD;
        float sl = 0.f, sr = 0.f;
#pragma unroll
        for (int d = 0; d < D_HEAD; ++d) {
            float w = wrow[d];
            sl += w * alv[d];
            sr += w * arv[d];
        }
        walbt[(size_t)(rel * 4 + h) * K + f] = f2bf(sl);
        walbt[(size_t)(16 + rel * 4 + h) * K + f] = f2bf(sr);
        return;
    }
    i -= nWal;
    if (i < 96 * K) walbt[(size_t)32 * K + i] = 0;   // zero pad rows 32-127
}

__global__ __launch_bounds__(256) void cast_k(const float* __restrict__ in,
                                              unsigned short* __restrict__ out, int n4) {
    int i = blockIdx.x * 256 + threadIdx.x;
    if (i >= n4) return;
    float4 v = *(const float4*)(in + (size_t)i * 4);
    u16x4 o = {f2bf(v.x), f2bf(v.y), f2bf(v.z), f2bf(v.w)};
    *(u16x4*)(out + (size_t)i * 4) = o;
}

// ---------------- CSR build ----------------
__global__ __launch_bounds__(256) void count_k(const int* __restrict__ dst, int* __restrict__ cnt) {
    int e = blockIdx.x * 256 + threadIdx.x;
    if (e >= N_EDGES) return;
    int r = blockIdx.y;
    atomicAdd(&cnt[r * N_NODES + dst[(size_t)r * N_EDGES + e]], 1);
}

__global__ __launch_bounds__(SCAN_B) void scan1_k(const int* __restrict__ cnt,
                                                  int* __restrict__ row, int* __restrict__ bsum) {
    __shared__ int sdata[SCAN_B];
    int r = blockIdx.y;
    int n = blockIdx.x * SCAN_B + threadIdx.x;
    int v = (n < N_NODES) ? cnt[r * N_NODES + n] : 0;
    sdata[threadIdx.x] = v;
    __syncthreads();
    for (int off = 1; off < SCAN_B; off <<= 1) {
        int t = (threadIdx.x >= off) ? sdata[threadIdx.x - off] : 0;
        __syncthreads();
        sdata[threadIdx.x] += t;
        __syncthreads();
    }
    if (n < N_NODES) row[r * (N_NODES + 1) + n] = sdata[threadIdx.x] - v;
    if (threadIdx.x == SCAN_B - 1) bsum[r * NBLK + blockIdx.x] = sdata[threadIdx.x];
}

__global__ __launch_bounds__(512) void scan2_k(int* __restrict__ bsum) {
    __shared__ int sdata[512];
    int r = blockIdx.x;
    int v = (threadIdx.x < NBLK) ? bsum[r * NBLK + threadIdx.x] : 0;
    sdata[threadIdx.x] = v;
    __syncthreads();
    for (int off = 1; off < 512; off <<= 1) {
        int t = (threadIdx.x >= off) ? sdata[threadIdx.x - off] : 0;
        __syncthreads();
        sdata[threadIdx.x] += t;
        __syncthreads();
    }
    if (threadIdx.x < NBLK) bsum[r * NBLK + threadIdx.x] = sdata[threadIdx.x] - v;
}

__global__ __launch_bounds__(256) void scan3_k(int* __restrict__ row, const int* __restrict__ bsum) {
    int r = blockIdx.y;
    int n = blockIdx.x * 256 + threadIdx.x;
    if (n > N_NODES) return;
    if (n == N_NODES) { row[r * (N_NODES + 1) + N_NODES] = N_EDGES; return; }
    row[r * (N_NODES + 1) + n] += bsum[r * NBLK + n / SCAN_B];
}

__global__ __launch_bounds__(256) void fill_k(const int* __restrict__ src, const int* __restrict__ dst,
                                              const int* __restrict__ row, int* __restrict__ cursor,
                                              int* __restrict__ csr_src) {
    int e = blockIdx.x * 256 + threadIdx.x;
    if (e >= N_EDGES) return;
    int r = blockIdx.y;
    int s = src[(size_t)r * N_EDGES + e];
    int d = dst[(size_t)r * N_EDGES + e];
    int p = row[r * (N_NODES + 1) + d] + atomicAdd(&cursor[r * N_NODES + d], 1);
    csr_src[(size_t)r * N_EDGES + p] = s;
}

// ---------------- fused: single-pass edge softmax + gather + bias + act (2x unrolled) ----------------
__global__ __launch_bounds__(256) void gather_fused_k(const int* __restrict__ csr_srcAll,
                                                      const int* __restrict__ rowAll,
                                                      const unsigned short* __restrict__ featAll,
                                                      const float* __restrict__ el,
                                                      const float* __restrict__ er,
                                                      const float* __restrict__ bias,  // [R][128]
                                                      unsigned short* __restrict__ hbf,
                                                      int relu) {
    int j = blockIdx.x * 256 + threadIdx.x;      // n*16 + sub
    if (j >= N_NODES * 16) return;
    int n = j >> 4, sub = j & 15;
    int h = sub >> 2;
    float acc[8];
#pragma unroll
    for (int q = 0; q < 8; ++q) acc[q] = 0.f;

#pragma unroll
    for (int rel = 0; rel < N_REL; ++rel) {
        const int* row = rowAll + (size_t)rel * (N_NODES + 1);
        const int* cs = csr_srcAll + (size_t)rel * N_EDGES;
        const float* elr = el + (size_t)rel * N_NODES * N_HEAD;
        const unsigned short* feat = featAll + (size_t)rel * N_NODES * F_HID;
        int st = row[n], en = row[n + 1];
        if (st == en) continue;
        float erd = er[(size_t)rel * N_NODES * N_HEAD + n * 4 + h];
        float sum = 0.f;
        float racc[8];
#pragma unroll
        for (int q = 0; q < 8; ++q) racc[q] = 0.f;
        int p = st;
        for (; p + 2 <= en; p += 2) {
            int s0 = cs[p], s1 = cs[p + 1];
            float e0 = elr[s0 * 4 + h];
            float e1 = elr[s1 * 4 + h];
            u16x8 f0 = *(const u16x8*)(feat + (size_t)s0 * F_HID + sub * 8);
            u16x8 f1 = *(const u16x8*)(feat + (size_t)s1 * F_HID + sub * 8);
            float v0 = e0 + erd; v0 = v0 > 0.f ? v0 : LRELU_SLOPE * v0;
            float v1 = e1 + erd; v1 = v1 > 0.f ? v1 : LRELU_SLOPE * v1;
            float ee0 = __expf(v0), ee1 = __expf(v1);
            sum += ee0; sum += ee1;
#pragma unroll
            for (int q = 0; q < 8; ++q) {
                racc[q] += ee0 * bf2f(f0[q]);
                racc[q] += ee1 * bf2f(f1[q]);
            }
        }
        if (p < en) {
            int s = cs[p];
            float v = elr[s * 4 + h] + erd;
            v = v > 0.f ? v : LRELU_SLOPE * v;
            float ee = __expf(v);
            sum += ee;
            u16x8 f = *(const u16x8*)(feat + (size_t)s * F_HID + sub * 8);
#pragma unroll
            for (int q = 0; q < 8; ++q) racc[q] += ee * bf2f(f[q]);
        }
        float id = 1.f / fmaxf(sum, 1e-30f);
#pragma unroll
        for (int q = 0; q < 8; ++q) acc[q] += racc[q] * id;
    }

    int c0 = sub * 8;
    u16x8 o;
#pragma unroll
    for (int q = 0; q < 8; ++q) {
        int c = c0 + q;
        float bs = bias[c] + bias[128 + c] + bias[256 + c] + bias[384 + c];
        float t = acc[q] + bs;
        if (relu) t = fmaxf(t, 0.f);
        o[q] = f2bf(t);
    }
    *(u16x8*)(hbf + (size_t)n * F_HID + c0) = o;
}

// out[N,64] = H_bf16[N,128] @ W[128,64] + b
__global__ __launch_bounds__(256) void fc_k(const unsigned short* __restrict__ Hm,
                                            const float* __restrict__ Wm,
                                            const float* __restrict__ bv,
                                            float* __restrict__ out) {
    __shared__ float Ws[F_HID][F_OUT];
    __shared__ float Hs[32][F_HID];
    const int tid = threadIdx.x;
    const int n0 = blockIdx.x * 32;
    const int tx = tid & 63, ty = tid >> 6;
#pragma unroll
    for (int l = 0; l < 8; ++l) {
        int flat = tid + l * 256;
        int r = flat >> 4, c4 = flat & 15;
        *(float4*)(&Ws[r][c4 * 4]) = *(const float4*)(Wm + r * F_OUT + c4 * 4);
    }
#pragma unroll
    for (int l = 0; l < 2; ++l) {
        int flat = tid + l * 256;
        int r = flat >> 4, c8 = flat & 15;
        u16x8 v = (u16x8)0;
        if (n0 + r < N_NODES)
            v = *(const u16x8*)(Hm + (size_t)(n0 + r) * F_HID + c8 * 8);
#pragma unroll
        for (int q = 0; q < 8; ++q) Hs[r][c8 * 8 + q] = bf2f(v[q]);
    }
    __syncthreads();
    float acc[8];
#pragma unroll
    for (int i = 0; i < 8; ++i) acc[i] = 0.f;
    for (int k = 0; k < F_HID; ++k) {
        float w = Ws[k][tx];
#pragma unroll
        for (int i = 0; i < 8; ++i) acc[i] += Hs[ty * 8 + i][k] * w;
    }
    float bb = bv[tx];
#pragma unroll
    for (int i = 0; i < 8; ++i) {
        int r = n0 + ty * 8 + i;
        if (r < N_NODES) out[(size_t)r * F_OUT + tx] = acc[i] + bb;
    }
}

extern "C" void kernel_launch(void* const* d_in, const int* in_sizes, int n_in,
                              void* d_out, int out_size, void* d_ws, size_t ws_size,
                              hipStream_t stream) {
    const float* x   = (const float*)d_in[0];
    const int*   src = (const int*)d_in[1];
    const int*   dst = (const int*)d_in[2];
    const float* W[3]  = {(const float*)d_in[3], (const float*)d_in[7],  (const float*)d_in[11]};
    const float* al[3] = {(const float*)d_in[4], (const float*)d_in[8],  (const float*)d_in[12]};
    const float* ar[3] = {(const float*)d_in[5], (const float*)d_in[9],  (const float*)d_in[13]};
    const float* bb[3] = {(const float*)d_in[6], (const float*)d_in[10], (const float*)d_in[14]};
    const float* fcW = (const float*)d_in[15];
    const float* fcb = (const float*)d_in[16];
    float* out = (float*)d_out;

    // ---- workspace layout ----
    char* p = (char*)d_ws;
    unsigned short* hbf   = (unsigned short*)p; p += (size_t)N_NODES * F_IN * 2;           // 51.2 MB
    unsigned short* featb = (unsigned short*)p; p += (size_t)N_REL * N_NODES * F_HID * 2;  // 102.4 MB
    float* el    = (float*)p;               p += (size_t)N_REL * N_NODES * N_HEAD * 4;     // 6.4 MB
    float* er    = (float*)p;               p += (size_t)N_REL * N_NODES * N_HEAD * 4;
    unsigned short* walbt0 = (unsigned short*)p; p += (size_t)128 * F_IN * 2;
    unsigned short* walbt1 = (unsigned short*)p; p += (size_t)128 * F_HID * 2;
    unsigned short* walbt2 = (unsigned short*)p; p += (size_t)128 * F_HID * 2;
    unsigned short* Wt0   = (unsigned short*)p; p += (size_t)N_REL * F_IN * F_HID * 2;
    unsigned short* Wt1   = (unsigned short*)p; p += (size_t)N_REL * F_HID * F_HID * 2;
    unsigned short* Wt2   = (unsigned short*)p; p += (size_t)N_REL * F_HID * F_HID * 2;
    int* cnt     = (int*)p;                 p += (size_t)N_REL * N_NODES * 4;
    int* cursor  = (int*)p;                 p += (size_t)N_REL * N_NODES * 4;
    int* rowp    = (int*)p;                 p += (size_t)N_REL * (N_NODES + 1) * 4;
    int* bsum    = (int*)p;                 p += (size_t)N_REL * NBLK * 4;
    int* csr_src = (int*)p;                 p += (size_t)N_REL * N_EDGES * 4;

    const int eblk = (N_EDGES + 255) / 256;
    const dim3 egrid(eblk, N_REL);

    // ---- prep (once per call) ----
    cast_k<<<(N_NODES * F_IN / 4 + 255) / 256, 256, 0, stream>>>(x, hbf, N_NODES * F_IN / 4);
    wprep2_k<F_IN><<<(N_REL * F_IN * 132 + 96 * F_IN + 255) / 256, 256, 0, stream>>>(
        W[0], al[0], ar[0], Wt0, walbt0);
    wprep2_k<F_HID><<<(N_REL * F_HID * 132 + 96 * F_HID + 255) / 256, 256, 0, stream>>>(
        W[1], al[1], ar[1], Wt1, walbt1);
    wprep2_k<F_HID><<<(N_REL * F_HID * 132 + 96 * F_HID + 255) / 256, 256, 0, stream>>>(
        W[2], al[2], ar[2], Wt2, walbt2);

    hipMemsetAsync(cnt, 0, 2 * (size_t)N_REL * N_NODES * sizeof(int), stream);
    count_k<<<egrid, 256, 0, stream>>>(dst, cnt);
    scan1_k<<<dim3(NBLK, N_REL), SCAN_B, 0, stream>>>(cnt, rowp, bsum);
    scan2_k<<<N_REL, 512, 0, stream>>>(bsum);
    scan3_k<<<dim3((N_NODES + 256) / 256, N_REL), 256, 0, stream>>>(rowp, bsum);
    fill_k<<<egrid, 256, 0, stream>>>(src, dst, rowp, cursor, csr_src);

    const dim3 gemm_grid(N_REL + 1, (N_NODES + 127) / 128);      // rel fast-varying; slot 4 = el/er
    const int g_blocks  = (N_NODES * 16 + 255) / 256;            // 6250
    const int fc_blocks = (N_NODES + 31) / 32;

    const unsigned short* Wts[3] = {Wt0, Wt1, Wt2};
    const unsigned short* walbts[3] = {walbt0, walbt1, walbt2};

    for (int layer = 0; layer < 3; ++layer) {
        if (layer == 0)
            gemm_mfma_k<F_IN><<<gemm_grid, 256, 0, stream>>>(hbf, Wts[0], walbts[0],
                                                             featb, el, er);
        else
            gemm_mfma_k<F_HID><<<gemm_grid, 256, 0, stream>>>(hbf, Wts[layer], walbts[layer],
                                                              featb, el, er);
        gather_fused_k<<<g_blocks, 256, 0, stream>>>(csr_src, rowp, featb, el, er,
                                                     bb[layer], hbf, layer < 2 ? 1 : 0);
    }
    fc_k<<<fc_blocks, 256, 0, stream>>>(hbf, fcW, fcb, out);
}

// Round 10
// 512.506 us; speedup vs baseline: 1.1990x; 1.0165x over previous
//
#include <hip/hip_runtime.h>
#include <hip/hip_bf16.h>

#define N_NODES 100000
#define N_EDGES 250000
#define N_REL 4
#define N_HEAD 4
#define D_HEAD 32
#define F_IN 256
#define F_HID 128
#define F_OUT 64
#define LRELU_SLOPE 0.2f

#define N_TILES 782                      // ceil(100000/128)
#define N_TGRP ((N_TILES + 7) / 8)       // 98
#define GEMM_BLOCKS (N_TGRP * 40)        // 3920: 8 tiles x 5 rel-slots per group

#define SCAN_B 256
#define NBLK ((N_NODES + SCAN_B - 1) / SCAN_B)   // 391

typedef __attribute__((ext_vector_type(8))) short s16x8;
typedef __attribute__((ext_vector_type(8))) unsigned short u16x8;
typedef __attribute__((ext_vector_type(4))) unsigned short u16x4;
typedef __attribute__((ext_vector_type(4))) float f32x4;

__device__ __forceinline__ float bf2f(unsigned short u) {
    return __uint_as_float(((unsigned int)u) << 16);
}
__device__ __forceinline__ unsigned short f2bf(float f) {
    unsigned int x = __float_as_uint(f);
    unsigned int r = x + 0x7fffu + ((x >> 16) & 1u);
    return (unsigned short)(r >> 16);
}
__device__ __forceinline__ void gload_lds16(const void* g, void* l) {
    __builtin_amdgcn_global_load_lds(
        (const __attribute__((address_space(1))) unsigned int*)g,
        (__attribute__((address_space(3))) unsigned int*)l, 16, 0, 0);
}

// ---------------- MFMA GEMM, XCD-locality swizzled 1D grid ----------------
// g -> (rel, tile): all 5 rel-slots of a tile land on the SAME XCD (g % 8 == tile % 8),
// 8 dispatch slots apart, so the A-tile is L2-hot across rel-slots.
// rel<4: C[r][N,128] = A[N,FIN] @ Bt[r][128,FIN]^T (bf16 out)
// rel==4: el/er[R][N][H] = A @ WalBt[32,FIN]^T (f32 out)
// MFMA operands SWAPPED (b in A-slot): lane holds channels cbase..cbase+3 of node row r.
template<int FIN>
__global__ __launch_bounds__(256) void gemm_mfma_k(const unsigned short* __restrict__ A,
                                                   const unsigned short* __restrict__ BtAll,
                                                   const unsigned short* __restrict__ WalBt,
                                                   unsigned short* __restrict__ CAll,
                                                   float* __restrict__ el,
                                                   float* __restrict__ er) {
    const int g = blockIdx.x;
    const int grp = g / 40;
    const int rem = g - grp * 40;
    const int rel = rem >> 3;                    // 0..4
    const int t = grp * 8 + (rem & 7);
    if (t >= N_TILES) return;
    const int row0 = t * 128;
    const unsigned short* Bt = (rel < N_REL) ? BtAll + (size_t)rel * F_HID * FIN : WalBt;

    __shared__ short As[128 * 64];   // [row][k] bf16, XOR-swizzled chunks
    __shared__ short Bs[128 * 64];
    const int tid = threadIdx.x;
    const int lane = tid & 63;
    const int wave = tid >> 6;
    const int wr = wave >> 1, wc = wave & 1;

    f32x4 acc[4][4];
#pragma unroll
    for (int m = 0; m < 4; ++m)
#pragma unroll
        for (int n = 0; n < 4; ++n) acc[m][n] = (f32x4)0.f;

    for (int k0 = 0; k0 < FIN; k0 += 64) {
        if (k0) __syncthreads();
#pragma unroll
        for (int i = 0; i < 4; ++i) {
            int flat = i * 256 + tid;
            int r = flat >> 3, ch = flat & 7;
            int sch = ch ^ (r & 7);
            int grow = row0 + r; if (grow > N_NODES - 1) grow = N_NODES - 1;
            gload_lds16(A + (size_t)grow * FIN + k0 + sch * 8, As + (size_t)flat * 8);
        }
#pragma unroll
        for (int i = 0; i < 4; ++i) {
            int flat = i * 256 + tid;
            int r = flat >> 3, ch = flat & 7;
            int sch = ch ^ (r & 7);
            gload_lds16(Bt + (size_t)r * FIN + k0 + sch * 8, Bs + (size_t)flat * 8);
        }
        __syncthreads();
#pragma unroll
        for (int kk = 0; kk < 2; ++kk) {
            s16x8 a[4], b[4];
            const int kb = kk * 64 + (lane >> 4) * 16;
#pragma unroll
            for (int m = 0; m < 4; ++m) {
                int r = wr * 64 + m * 16 + (lane & 15);
                int off = r * 128 + (kb ^ ((r & 7) << 4));
                a[m] = *(const s16x8*)((const char*)As + off);
            }
#pragma unroll
            for (int n = 0; n < 4; ++n) {
                int r = wc * 64 + n * 16 + (lane & 15);
                int off = r * 128 + (kb ^ ((r & 7) << 4));
                b[n] = *(const s16x8*)((const char*)Bs + off);
            }
#pragma unroll
            for (int m = 0; m < 4; ++m)
#pragma unroll
                for (int n = 0; n < 4; ++n)
                    acc[m][n] = __builtin_amdgcn_mfma_f32_16x16x32_bf16(b[n], a[m], acc[m][n], 0, 0, 0);
        }
    }
    if (rel < N_REL) {
        unsigned short* C = CAll + (size_t)rel * N_NODES * F_HID;
#pragma unroll
        for (int m = 0; m < 4; ++m) {
            int r = row0 + wr * 64 + m * 16 + (lane & 15);
            if (r < N_NODES) {
#pragma unroll
                for (int n = 0; n < 4; ++n) {
                    int cbase = wc * 64 + n * 16 + (lane >> 4) * 4;
                    u16x4 o = {f2bf(acc[m][n][0]), f2bf(acc[m][n][1]),
                               f2bf(acc[m][n][2]), f2bf(acc[m][n][3])};
                    *(u16x4*)(C + (size_t)r * F_HID + cbase) = o;
                }
            }
        }
    } else if (wc == 0) {
        int relh = lane >> 4;
#pragma unroll
        for (int m = 0; m < 4; ++m) {
            int r = row0 + wr * 64 + m * 16 + (lane & 15);
            if (r < N_NODES) {
                *(f32x4*)(el + (size_t)relh * N_NODES * N_HEAD + r * 4) = acc[m][0];
                *(f32x4*)(er + (size_t)relh * N_NODES * N_HEAD + r * 4) = acc[m][1];
            }
        }
    }
}

// ---------------- weight prep: Wt transpose + WalBt[128][K] bf16 (rows 32-127 zero) ----------------
template<int K>
__global__ __launch_bounds__(256) void wprep2_k(const float* __restrict__ W,
                                                const float* __restrict__ al,
                                                const float* __restrict__ ar,
                                                unsigned short* __restrict__ Wt,
                                                unsigned short* __restrict__ walbt) {
    int i = blockIdx.x * 256 + threadIdx.x;
    const int nWt = N_REL * K * 128;
    if (i < nWt) {
        int r = i / (K * 128);
        int rem = i - r * K * 128;
        int k = rem >> 7, n = rem & 127;
        Wt[(size_t)r * 128 * K + (size_t)n * K + k] = f2bf(W[i]);
        return;
    }
    i -= nWt;
    const int nWal = N_REL * K * 4;
    if (i < nWal) {
        int rel = i / (K * 4);
        int rem = i - rel * K * 4;
        int f = rem >> 2, h = rem & 3;
        const float* wrow = W + ((size_t)rel * K + f) * F_HID + h * D_HEAD;
        const float* alv = al + ((size_t)rel * N_HEAD + h) * D_HEAD;
        const float* arv = ar + ((size_t)rel * N_HEAD + h) * D_HEAD;
        float sl = 0.f, sr = 0.f;
#pragma unroll
        for (int d = 0; d < D_HEAD; ++d) {
            float w = wrow[d];
            sl += w * alv[d];
            sr += w * arv[d];
        }
        walbt[(size_t)(rel * 4 + h) * K + f] = f2bf(sl);
        walbt[(size_t)(16 + rel * 4 + h) * K + f] = f2bf(sr);
        return;
    }
    i -= nWal;
    if (i < 96 * K) walbt[(size_t)32 * K + i] = 0;   // zero pad rows 32-127
}

__global__ __launch_bounds__(256) void cast_k(const float* __restrict__ in,
                                              unsigned short* __restrict__ out, int n4) {
    int i = blockIdx.x * 256 + threadIdx.x;
    if (i >= n4) return;
    float4 v = *(const float4*)(in + (size_t)i * 4);
    u16x4 o = {f2bf(v.x), f2bf(v.y), f2bf(v.z), f2bf(v.w)};
    *(u16x4*)(out + (size_t)i * 4) = o;
}

// ---------------- CSR build ----------------
__global__ __launch_bounds__(256) void count_k(const int* __restrict__ dst, int* __restrict__ cnt) {
    int e = blockIdx.x * 256 + threadIdx.x;
    if (e >= N_EDGES) return;
    int r = blockIdx.y;
    atomicAdd(&cnt[r * N_NODES + dst[(size_t)r * N_EDGES + e]], 1);
}

__global__ __launch_bounds__(SCAN_B) void scan1_k(const int* __restrict__ cnt,
                                                  int* __restrict__ row, int* __restrict__ bsum) {
    __shared__ int sdata[SCAN_B];
    int r = blockIdx.y;
    int n = blockIdx.x * SCAN_B + threadIdx.x;
    int v = (n < N_NODES) ? cnt[r * N_NODES + n] : 0;
    sdata[threadIdx.x] = v;
    __syncthreads();
    for (int off = 1; off < SCAN_B; off <<= 1) {
        int t = (threadIdx.x >= off) ? sdata[threadIdx.x - off] : 0;
        __syncthreads();
        sdata[threadIdx.x] += t;
        __syncthreads();
    }
    if (n < N_NODES) row[r * (N_NODES + 1) + n] = sdata[threadIdx.x] - v;
    if (threadIdx.x == SCAN_B - 1) bsum[r * NBLK + blockIdx.x] = sdata[threadIdx.x];
}

__global__ __launch_bounds__(512) void scan2_k(int* __restrict__ bsum) {
    __shared__ int sdata[512];
    int r = blockIdx.x;
    int v = (threadIdx.x < NBLK) ? bsum[r * NBLK + threadIdx.x] : 0;
    sdata[threadIdx.x] = v;
    __syncthreads();
    for (int off = 1; off < 512; off <<= 1) {
        int t = (threadIdx.x >= off) ? sdata[threadIdx.x - off] : 0;
        __syncthreads();
        sdata[threadIdx.x] += t;
        __syncthreads();
    }
    if (threadIdx.x < NBLK) bsum[r * NBLK + threadIdx.x] = sdata[threadIdx.x] - v;
}

__global__ __launch_bounds__(256) void scan3_k(int* __restrict__ row, const int* __restrict__ bsum) {
    int r = blockIdx.y;
    int n = blockIdx.x * 256 + threadIdx.x;
    if (n > N_NODES) return;
    if (n == N_NODES) { row[r * (N_NODES + 1) + N_NODES] = N_EDGES; return; }
    row[r * (N_NODES + 1) + n] += bsum[r * NBLK + n / SCAN_B];
}

__global__ __launch_bounds__(256) void fill_k(const int* __restrict__ src, const int* __restrict__ dst,
                                              const int* __restrict__ row, int* __restrict__ cursor,
                                              int* __restrict__ csr_src) {
    int e = blockIdx.x * 256 + threadIdx.x;
    if (e >= N_EDGES) return;
    int r = blockIdx.y;
    int s = src[(size_t)r * N_EDGES + e];
    int d = dst[(size_t)r * N_EDGES + e];
    int p = row[r * (N_NODES + 1) + d] + atomicAdd(&cursor[r * N_NODES + d], 1);
    csr_src[(size_t)r * N_EDGES + p] = s;
}

// ---------------- fused: single-pass edge softmax + gather + bias + act (2x unrolled) ----------------
__global__ __launch_bounds__(256) void gather_fused_k(const int* __restrict__ csr_srcAll,
                                                      const int* __restrict__ rowAll,
                                                      const unsigned short* __restrict__ featAll,
                                                      const float* __restrict__ el,
                                                      const float* __restrict__ er,
                                                      const float* __restrict__ bias,  // [R][128]
                                                      unsigned short* __restrict__ hbf,
                                                      int relu) {
    int j = blockIdx.x * 256 + threadIdx.x;      // n*16 + sub
    if (j >= N_NODES * 16) return;
    int n = j >> 4, sub = j & 15;
    int h = sub >> 2;
    float acc[8];
#pragma unroll
    for (int q = 0; q < 8; ++q) acc[q] = 0.f;

#pragma unroll
    for (int rel = 0; rel < N_REL; ++rel) {
        const int* row = rowAll + (size_t)rel * (N_NODES + 1);
        const int* cs = csr_srcAll + (size_t)rel * N_EDGES;
        const float* elr = el + (size_t)rel * N_NODES * N_HEAD;
        const unsigned short* feat = featAll + (size_t)rel * N_NODES * F_HID;
        int st = row[n], en = row[n + 1];
        if (st == en) continue;
        float erd = er[(size_t)rel * N_NODES * N_HEAD + n * 4 + h];
        float sum = 0.f;
        float racc[8];
#pragma unroll
        for (int q = 0; q < 8; ++q) racc[q] = 0.f;
        int p = st;
        for (; p + 2 <= en; p += 2) {
            int s0 = cs[p], s1 = cs[p + 1];
            float e0 = elr[s0 * 4 + h];
            float e1 = elr[s1 * 4 + h];
            u16x8 f0 = *(const u16x8*)(feat + (size_t)s0 * F_HID + sub * 8);
            u16x8 f1 = *(const u16x8*)(feat + (size_t)s1 * F_HID + sub * 8);
            float v0 = e0 + erd; v0 = v0 > 0.f ? v0 : LRELU_SLOPE * v0;
            float v1 = e1 + erd; v1 = v1 > 0.f ? v1 : LRELU_SLOPE * v1;
            float ee0 = __expf(v0), ee1 = __expf(v1);
            sum += ee0; sum += ee1;
#pragma unroll
            for (int q = 0; q < 8; ++q) {
                racc[q] += ee0 * bf2f(f0[q]);
                racc[q] += ee1 * bf2f(f1[q]);
            }
        }
        if (p < en) {
            int s = cs[p];
            float v = elr[s * 4 + h] + erd;
            v = v > 0.f ? v : LRELU_SLOPE * v;
            float ee = __expf(v);
            sum += ee;
            u16x8 f = *(const u16x8*)(feat + (size_t)s * F_HID + sub * 8);
#pragma unroll
            for (int q = 0; q < 8; ++q) racc[q] += ee * bf2f(f[q]);
        }
        float id = 1.f / fmaxf(sum, 1e-30f);
#pragma unroll
        for (int q = 0; q < 8; ++q) acc[q] += racc[q] * id;
    }

    int c0 = sub * 8;
    u16x8 o;
#pragma unroll
    for (int q = 0; q < 8; ++q) {
        int c = c0 + q;
        float bs = bias[c] + bias[128 + c] + bias[256 + c] + bias[384 + c];
        float t = acc[q] + bs;
        if (relu) t = fmaxf(t, 0.f);
        o[q] = f2bf(t);
    }
    *(u16x8*)(hbf + (size_t)n * F_HID + c0) = o;
}

// out[N,64] = H_bf16[N,128] @ W[128,64] + b
__global__ __launch_bounds__(256) void fc_k(const unsigned short* __restrict__ Hm,
                                            const float* __restrict__ Wm,
                                            const float* __restrict__ bv,
                                            float* __restrict__ out) {
    __shared__ float Ws[F_HID][F_OUT];
    __shared__ float Hs[32][F_HID];
    const int tid = threadIdx.x;
    const int n0 = blockIdx.x * 32;
    const int tx = tid & 63, ty = tid >> 6;
#pragma unroll
    for (int l = 0; l < 8; ++l) {
        int flat = tid + l * 256;
        int r = flat >> 4, c4 = flat & 15;
        *(float4*)(&Ws[r][c4 * 4]) = *(const float4*)(Wm + r * F_OUT + c4 * 4);
    }
#pragma unroll
    for (int l = 0; l < 2; ++l) {
        int flat = tid + l * 256;
        int r = flat >> 4, c8 = flat & 15;
        u16x8 v = (u16x8)0;
        if (n0 + r < N_NODES)
            v = *(const u16x8*)(Hm + (size_t)(n0 + r) * F_HID + c8 * 8);
#pragma unroll
        for (int q = 0; q < 8; ++q) Hs[r][c8 * 8 + q] = bf2f(v[q]);
    }
    __syncthreads();
    float acc[8];
#pragma unroll
    for (int i = 0; i < 8; ++i) acc[i] = 0.f;
    for (int k = 0; k < F_HID; ++k) {
        float w = Ws[k][tx];
#pragma unroll
        for (int i = 0; i < 8; ++i) acc[i] += Hs[ty * 8 + i][k] * w;
    }
    float bb = bv[tx];
#pragma unroll
    for (int i = 0; i < 8; ++i) {
        int r = n0 + ty * 8 + i;
        if (r < N_NODES) out[(size_t)r * F_OUT + tx] = acc[i] + bb;
    }
}

extern "C" void kernel_launch(void* const* d_in, const int* in_sizes, int n_in,
                              void* d_out, int out_size, void* d_ws, size_t ws_size,
                              hipStream_t stream) {
    const float* x   = (const float*)d_in[0];
    const int*   src = (const int*)d_in[1];
    const int*   dst = (const int*)d_in[2];
    const float* W[3]  = {(const float*)d_in[3], (const float*)d_in[7],  (const float*)d_in[11]};
    const float* al[3] = {(const float*)d_in[4], (const float*)d_in[8],  (const float*)d_in[12]};
    const float* ar[3] = {(const float*)d_in[5], (const float*)d_in[9],  (const float*)d_in[13]};
    const float* bb[3] = {(const float*)d_in[6], (const float*)d_in[10], (const float*)d_in[14]};
    const float* fcW = (const float*)d_in[15];
    const float* fcb = (const float*)d_in[16];
    float* out = (float*)d_out;

    // ---- workspace layout ----
    char* p = (char*)d_ws;
    unsigned short* hbf   = (unsigned short*)p; p += (size_t)N_NODES * F_IN * 2;           // 51.2 MB
    unsigned short* featb = (unsigned short*)p; p += (size_t)N_REL * N_NODES * F_HID * 2;  // 102.4 MB
    float* el    = (float*)p;               p += (size_t)N_REL * N_NODES * N_HEAD * 4;     // 6.4 MB
    float* er    = (float*)p;               p += (size_t)N_REL * N_NODES * N_HEAD * 4;
    unsigned short* walbt0 = (unsigned short*)p; p += (size_t)128 * F_IN * 2;
    unsigned short* walbt1 = (unsigned short*)p; p += (size_t)128 * F_HID * 2;
    unsigned short* walbt2 = (unsigned short*)p; p += (size_t)128 * F_HID * 2;
    unsigned short* Wt0   = (unsigned short*)p; p += (size_t)N_REL * F_IN * F_HID * 2;
    unsigned short* Wt1   = (unsigned short*)p; p += (size_t)N_REL * F_HID * F_HID * 2;
    unsigned short* Wt2   = (unsigned short*)p; p += (size_t)N_REL * F_HID * F_HID * 2;
    int* cnt     = (int*)p;                 p += (size_t)N_REL * N_NODES * 4;
    int* cursor  = (int*)p;                 p += (size_t)N_REL * N_NODES * 4;
    int* rowp    = (int*)p;                 p += (size_t)N_REL * (N_NODES + 1) * 4;
    int* bsum    = (int*)p;                 p += (size_t)N_REL * NBLK * 4;
    int* csr_src = (int*)p;                 p += (size_t)N_REL * N_EDGES * 4;

    const int eblk = (N_EDGES + 255) / 256;
    const dim3 egrid(eblk, N_REL);

    // ---- prep (once per call) ----
    cast_k<<<(N_NODES * F_IN / 4 + 255) / 256, 256, 0, stream>>>(x, hbf, N_NODES * F_IN / 4);
    wprep2_k<F_IN><<<(N_REL * F_IN * 132 + 96 * F_IN + 255) / 256, 256, 0, stream>>>(
        W[0], al[0], ar[0], Wt0, walbt0);
    wprep2_k<F_HID><<<(N_REL * F_HID * 132 + 96 * F_HID + 255) / 256, 256, 0, stream>>>(
        W[1], al[1], ar[1], Wt1, walbt1);
    wprep2_k<F_HID><<<(N_REL * F_HID * 132 + 96 * F_HID + 255) / 256, 256, 0, stream>>>(
        W[2], al[2], ar[2], Wt2, walbt2);

    hipMemsetAsync(cnt, 0, 2 * (size_t)N_REL * N_NODES * sizeof(int), stream);
    count_k<<<egrid, 256, 0, stream>>>(dst, cnt);
    scan1_k<<<dim3(NBLK, N_REL), SCAN_B, 0, stream>>>(cnt, rowp, bsum);
    scan2_k<<<N_REL, 512, 0, stream>>>(bsum);
    scan3_k<<<dim3((N_NODES + 256) / 256, N_REL), 256, 0, stream>>>(rowp, bsum);
    fill_k<<<egrid, 256, 0, stream>>>(src, dst, rowp, cursor, csr_src);

    const int g_blocks  = (N_NODES * 16 + 255) / 256;            // 6250
    const int fc_blocks = (N_NODES + 31) / 32;

    const unsigned short* Wts[3] = {Wt0, Wt1, Wt2};
    const unsigned short* walbts[3] = {walbt0, walbt1, walbt2};

    for (int layer = 0; layer < 3; ++layer) {
        if (layer == 0)
            gemm_mfma_k<F_IN><<<GEMM_BLOCKS, 256, 0, stream>>>(hbf, Wts[0], walbts[0],
                                                               featb, el, er);
        else
            gemm_mfma_k<F_HID><<<GEMM_BLOCKS, 256, 0, stream>>>(hbf, Wts[layer], walbts[layer],
                                                                featb, el, er);
        gather_fused_k<<<g_blocks, 256, 0, stream>>>(csr_src, rowp, featb, el, er,
                                                     bb[layer], hbf, layer < 2 ? 1 : 0);
    }
    fc_k<<<fc_blocks, 256, 0, stream>>>(hbf, fcW, fcb, out);
}